// Round 1
// baseline (2087.338 us; speedup 1.0000x reference)
//
#include <hip/hip_runtime.h>
#include <stdint.h>

#define HID 512
#define BM 128
#define BN 128
#define BK 64

typedef __attribute__((ext_vector_type(8))) short bf16x8;
typedef __attribute__((ext_vector_type(4))) short short4v;
typedef __attribute__((ext_vector_type(4))) float f32x4;

__device__ __forceinline__ unsigned short f2bf_rne(float f) {
  unsigned u = __float_as_uint(f);
  unsigned r = u + 0x7fffu + ((u >> 16) & 1u);
  return (unsigned short)(r >> 16);
}

__device__ __forceinline__ void gload_lds16(const void* g, void* l) {
  auto gp = reinterpret_cast<const __attribute__((address_space(1))) unsigned int*>(
      (unsigned long long)(uintptr_t)g);
  auto lp = reinterpret_cast<__attribute__((address_space(3))) unsigned int*>(
      (unsigned int)(uintptr_t)l);
  __builtin_amdgcn_global_load_lds(gp, lp, 16, 0, 0);
}

// Transpose + RNE hi/lo split: W [K][N] fp32 -> Bt_hi/Bt_lo [N][K] bf16 bits
__global__ void trans_split_kernel(const float* __restrict__ W,
                                   short* __restrict__ Bth, short* __restrict__ Btl,
                                   int kbits, int N) {
  int id = blockIdx.x * 256 + threadIdx.x;
  int K = 1 << kbits;
  if (id >= N * K) return;
  int n = id >> kbits;
  int k = id & (K - 1);
  float w = W[(size_t)k * N + n];
  unsigned short hi = f2bf_rne(w);
  float rem = w - __uint_as_float(((unsigned)hi) << 16);
  unsigned short lo = f2bf_rne(rem);
  Bth[id] = (short)hi;
  Btl[id] = (short)lo;
}

__global__ void init_out_kernel(float* __restrict__ out, const float* __restrict__ p3b, int n) {
  int id = blockIdx.x * 256 + threadIdx.x;
  if (id < n) out[id] = p3b[0];
}

// MODE: 0 = C=relu(A@Bt^T+bias)
//       1 = C=relu(A@Bt^T+bias)+A          (residual)
//       2 = C=relu([h[src],h[dst]]@Bt^T+b) (gather, K=1024)
//       3 = score += dot(relu(A@Bt^T+b), p3)  (fused final projection)
template <int MODE>
__global__ __launch_bounds__(256, 2) void gemm_kernel(
    const float* __restrict__ A,      // [M][512] fp32 (MODE2: h [N_NODES][512])
    const short* __restrict__ Bth,    // [512][KB] bf16-hi bits
    const short* __restrict__ Btl,    // [512][KB] bf16-lo bits
    const float* __restrict__ bias,   // [512]
    const int* __restrict__ isrc, const int* __restrict__ idst,  // MODE 2
    const float* __restrict__ p3,     // [512] (MODE 3)
    float* __restrict__ Cout,         // [M][512] (MODE 0,1,2)
    float* __restrict__ score,        // [M]      (MODE 3)
    int M) {
  constexpr int KB = (MODE == 2) ? 1024 : 512;
  constexpr int KSTEPS = KB / BK;

  __shared__ short AhL[BM * BK];
  __shared__ short AlL[BM * BK];
  __shared__ short BhL[BN * BK];
  __shared__ short BlL[BN * BK];

  const int tid = threadIdx.x;
  const int lane = tid & 63;
  const int wid = tid >> 6;
  const int wr = wid >> 1, wc = wid & 1;
  const int ln15 = lane & 15, lh = lane >> 4;
  const int m0 = blockIdx.y * BM;
  const int n0 = blockIdx.x * BN;

  // A-staging row indices: thread stages chunk-rows {i*16 + tid>>4}
  int rows0[8], rows1[8];
#pragma unroll
  for (int i = 0; i < 8; ++i) {
    int e = m0 + i * 16 + (tid >> 4);
    if (e > M - 1) e = M - 1;
    if (MODE == 2) {
      rows0[i] = isrc[e];
      rows1[i] = idst[e];
    } else {
      rows0[i] = e;
      rows1[i] = e;
    }
  }
  const int ja = tid & 15;  // float4 index within A row-chunk
  const int jb = tid & 7;   // 16B chunk within B row

  f32x4 acc[4][4];
  const f32x4 fzero = {0.f, 0.f, 0.f, 0.f};
#pragma unroll
  for (int i = 0; i < 4; ++i)
#pragma unroll
    for (int j = 0; j < 4; ++j) acc[i][j] = fzero;

  for (int ks = 0; ks < KSTEPS; ++ks) {
    const int k0 = ks * BK;
    // ---- stage B tiles via async global->LDS (16B) ----
#pragma unroll
    for (int i = 0; i < 4; ++i) {
      int c = i * 256 + tid;
      int brow = c >> 3;
      const size_t goff = (size_t)(n0 + brow) * KB + k0 + jb * 8;
      int lbase = (i * 256 + wid * 64) * 8;  // shorts
      gload_lds16(Bth + goff, &BhL[lbase]);
      gload_lds16(Btl + goff, &BlL[lbase]);
    }
    // ---- stage A: fp32 -> truncation-split bf16 hi/lo ----
    const int kA = (MODE == 2) ? (k0 & 511) : k0;
#pragma unroll
    for (int i = 0; i < 8; ++i) {
      int row = (MODE == 2) ? (ks < 8 ? rows0[i] : rows1[i]) : rows0[i];
      const f32x4 v = *reinterpret_cast<const f32x4*>(A + (size_t)row * HID + kA + ja * 4);
      short4v h4, l4;
#pragma unroll
      for (int q = 0; q < 4; ++q) {
        unsigned ua = __float_as_uint(v[q]);
        h4[q] = (short)(ua >> 16);
        float rem = v[q] - __uint_as_float(ua & 0xffff0000u);
        l4[q] = (short)(__float_as_uint(rem) >> 16);
      }
      int lrow = i * 16 + (tid >> 4);
      *reinterpret_cast<short4v*>(&AhL[lrow * BK + ja * 4]) = h4;
      *reinterpret_cast<short4v*>(&AlL[lrow * BK + ja * 4]) = l4;
    }
    __syncthreads();
    // ---- compute: 3 MFMAs per (i,j,kchunk) for split precision ----
#pragma unroll
    for (int kk = 0; kk < 2; ++kk) {
      const int ko = kk * 32 + lh * 8;
      bf16x8 ah[4], al[4], bh[4], bl[4];
#pragma unroll
      for (int i = 0; i < 4; ++i) {
        int ra = wr * 64 + i * 16 + ln15;
        ah[i] = *reinterpret_cast<const bf16x8*>(&AhL[ra * BK + ko]);
        al[i] = *reinterpret_cast<const bf16x8*>(&AlL[ra * BK + ko]);
      }
#pragma unroll
      for (int j = 0; j < 4; ++j) {
        int rb = wc * 64 + j * 16 + ln15;
        bh[j] = *reinterpret_cast<const bf16x8*>(&BhL[rb * BK + ko]);
        bl[j] = *reinterpret_cast<const bf16x8*>(&BlL[rb * BK + ko]);
      }
#pragma unroll
      for (int i = 0; i < 4; ++i)
#pragma unroll
        for (int j = 0; j < 4; ++j) {
          acc[i][j] = __builtin_amdgcn_mfma_f32_16x16x32_bf16(ah[i], bh[j], acc[i][j], 0, 0, 0);
          acc[i][j] = __builtin_amdgcn_mfma_f32_16x16x32_bf16(ah[i], bl[j], acc[i][j], 0, 0, 0);
          acc[i][j] = __builtin_amdgcn_mfma_f32_16x16x32_bf16(al[i], bh[j], acc[i][j], 0, 0, 0);
        }
    }
    __syncthreads();
  }

  // ---- epilogue ----
  float bj[4], p3j[4];
#pragma unroll
  for (int j = 0; j < 4; ++j) {
    int col = n0 + wc * 64 + j * 16 + ln15;
    bj[j] = bias[col];
    p3j[j] = (MODE == 3) ? p3[col] : 0.f;
  }

  if (MODE == 3) {
#pragma unroll
    for (int i = 0; i < 4; ++i) {
#pragma unroll
      for (int r = 0; r < 4; ++r) {
        float p = 0.f;
#pragma unroll
        for (int j = 0; j < 4; ++j) {
          float val = fmaxf(acc[i][j][r] + bj[j], 0.f);
          p += val * p3j[j];
        }
        // reduce over the 16 lanes holding this row's 16 columns
        p += __shfl_xor(p, 1);
        p += __shfl_xor(p, 2);
        p += __shfl_xor(p, 4);
        p += __shfl_xor(p, 8);
        int row = m0 + wr * 64 + i * 16 + lh * 4 + r;
        if (ln15 == 0 && row < M) atomicAdd(&score[row], p);
      }
    }
  } else {
#pragma unroll
    for (int i = 0; i < 4; ++i) {
#pragma unroll
      for (int j = 0; j < 4; ++j) {
        int col = n0 + wc * 64 + j * 16 + ln15;
#pragma unroll
        for (int r = 0; r < 4; ++r) {
          int row = m0 + wr * 64 + i * 16 + lh * 4 + r;
          if (row < M) {
            float val = fmaxf(acc[i][j][r] + bj[j], 0.f);
            if (MODE == 1) val += A[(size_t)row * HID + col];
            Cout[(size_t)row * HID + col] = val;
          }
        }
      }
    }
  }
}

extern "C" void kernel_launch(void* const* d_in, const int* in_sizes, int n_in,
                              void* d_out, int out_size, void* d_ws, size_t ws_size,
                              hipStream_t stream) {
  (void)n_in; (void)out_size; (void)ws_size;
  const float* x      = (const float*)d_in[0];
  const int* pos_src  = (const int*)d_in[1];
  const int* pos_dst  = (const int*)d_in[2];
  const int* neg_src  = (const int*)d_in[3];
  const int* neg_dst  = (const int*)d_in[4];
  const float* W1 = (const float*)d_in[5];
  const float* b1 = (const float*)d_in[6];
  const float* W2 = (const float*)d_in[7];
  const float* b2 = (const float*)d_in[8];
  const float* Wo = (const float*)d_in[9];
  const float* bo = (const float*)d_in[10];
  const float* P1w = (const float*)d_in[11];
  const float* P1b = (const float*)d_in[12];
  const float* P2w = (const float*)d_in[13];
  const float* P2b = (const float*)d_in[14];
  const float* P3w = (const float*)d_in[15];
  const float* P3b = (const float*)d_in[16];

  const int N_NODES = in_sizes[0] / HID;  // 100000
  const int E = in_sizes[1];              // 100000
  float* out = (float*)d_out;

  char* ws = (char*)d_ws;
  const size_t actBytes = (size_t)N_NODES * HID * sizeof(float);
  float* buf0 = (float*)ws;                 // h1, then h
  float* buf1 = (float*)(ws + actBytes);    // h2, then z1
  short* wp = (short*)(ws + 2 * actBytes);
  short* W1th = wp; wp += 512 * 512;
  short* W1tl = wp; wp += 512 * 512;
  short* W2th = wp; wp += 512 * 512;
  short* W2tl = wp; wp += 512 * 512;
  short* Woth = wp; wp += 512 * 512;
  short* Wotl = wp; wp += 512 * 512;
  short* P1th = wp; wp += 512 * 1024;
  short* P1tl = wp; wp += 512 * 1024;
  short* P2th = wp; wp += 512 * 512;
  short* P2tl = wp; wp += 512 * 512;

  // weight transpose + hi/lo split (tiny)
  trans_split_kernel<<<(512 * 512 + 255) / 256, 256, 0, stream>>>(W1, W1th, W1tl, 9, 512);
  trans_split_kernel<<<(512 * 512 + 255) / 256, 256, 0, stream>>>(W2, W2th, W2tl, 9, 512);
  trans_split_kernel<<<(512 * 512 + 255) / 256, 256, 0, stream>>>(Wo, Woth, Wotl, 9, 512);
  trans_split_kernel<<<(512 * 1024 + 255) / 256, 256, 0, stream>>>(P1w, P1th, P1tl, 10, 512);
  trans_split_kernel<<<(512 * 512 + 255) / 256, 256, 0, stream>>>(P2w, P2th, P2tl, 9, 512);
  init_out_kernel<<<(2 * E + 255) / 256, 256, 0, stream>>>(out, P3b, 2 * E);

  dim3 blk(256);
  dim3 grdN(4, (N_NODES + BM - 1) / BM);
  dim3 grdE(4, (E + BM - 1) / BM);

  // encoder: h1 = relu(x@W1+b1); h2 = relu(h1@W2+b2)+h1; h = relu(h2@Wo+bo)+h2
  gemm_kernel<0><<<grdN, blk, 0, stream>>>(x,    W1th, W1tl, b1, nullptr, nullptr, nullptr, buf0, nullptr, N_NODES);
  gemm_kernel<1><<<grdN, blk, 0, stream>>>(buf0, W2th, W2tl, b2, nullptr, nullptr, nullptr, buf1, nullptr, N_NODES);
  gemm_kernel<1><<<grdN, blk, 0, stream>>>(buf1, Woth, Wotl, bo, nullptr, nullptr, nullptr, buf0, nullptr, N_NODES);

  // positive edges: z1 = relu([h[s],h[d]]@P1+b); scores = relu(z1@P2+b2)@P3 + b3
  gemm_kernel<2><<<grdE, blk, 0, stream>>>(buf0, P1th, P1tl, P1b, pos_src, pos_dst, nullptr, buf1, nullptr, E);
  gemm_kernel<3><<<grdE, blk, 0, stream>>>(buf1, P2th, P2tl, P2b, nullptr, nullptr, P3w, nullptr, out, E);

  // negative edges
  gemm_kernel<2><<<grdE, blk, 0, stream>>>(buf0, P1th, P1tl, P1b, neg_src, neg_dst, nullptr, buf1, nullptr, E);
  gemm_kernel<3><<<grdE, blk, 0, stream>>>(buf1, P2th, P2tl, P2b, nullptr, nullptr, P3w, nullptr, out + E, E);
}

// Round 2
// 1712.425 us; speedup vs baseline: 1.2189x; 1.2189x over previous
//
#include <hip/hip_runtime.h>
#include <stdint.h>

#define HID 512
#define BM 128
#define BK 32
#define KSTEPS 16
#define THREADS 512

typedef __attribute__((ext_vector_type(8))) short bf16x8;
typedef __attribute__((ext_vector_type(8))) short short8v;
typedef __attribute__((ext_vector_type(4))) float f32x4;
typedef __attribute__((ext_vector_type(16))) float f32x16;

// LDS region offsets (in shorts) within one 80KB buffer
#define AH_OFF 0
#define AL_OFF 4096
#define BH_OFF 8192
#define BL_OFF 24576
#define LDS_SHORTS 40960

__device__ __forceinline__ unsigned short f2bf_rne(float f) {
  unsigned u = __float_as_uint(f);
  unsigned r = u + 0x7fffu + ((u >> 16) & 1u);
  return (unsigned short)(r >> 16);
}

__device__ __forceinline__ void gload_lds16(const void* g, void* l) {
  auto gp = reinterpret_cast<const __attribute__((address_space(1))) unsigned int*>(
      (unsigned long long)(uintptr_t)g);
  auto lp = reinterpret_cast<__attribute__((address_space(3))) unsigned int*>(
      (unsigned int)(uintptr_t)l);
  __builtin_amdgcn_global_load_lds(gp, lp, 16, 0, 0);
}

// Transpose + RNE hi/lo split: W [512][512] fp32 -> Bt_hi/Bt_lo [N][K] bf16 bits
__global__ void trans_split_kernel(const float* __restrict__ W,
                                   short* __restrict__ Bth, short* __restrict__ Btl) {
  int id = blockIdx.x * 256 + threadIdx.x;
  int n = id >> 9;
  int k = id & 511;
  float w = W[(size_t)k * 512 + n];
  unsigned short hi = f2bf_rne(w);
  float rem = w - __uint_as_float(((unsigned)hi) << 16);
  unsigned short lo = f2bf_rne(rem);
  Bth[id] = (short)hi;
  Btl[id] = (short)lo;
}

__global__ void init_out_kernel(float* __restrict__ out, const float* __restrict__ p3b, int n) {
  int id = blockIdx.x * 256 + threadIdx.x;
  if (id < n) out[id] = p3b[0];
}

// MODE: 0 = C = relu(A@Bt^T + bias)
//       1 = C = relu(A@Bt^T + bias) + A                  (residual)
//       2 = C = A@Bt^T (+ bias if non-null, no relu)     (U/V projections)
//       3 = score[row] += dot(relu( relu(U[s]+V[d]) @Bt^T + bias), p3)
template <int MODE>
__global__ __launch_bounds__(THREADS, 2) void gemm_kernel(
    const float* A, const float* A2,                       // MODE3: A=U, A2=V
    const short* __restrict__ Bth, const short* __restrict__ Btl,  // [512][512]
    const float* __restrict__ bias,                        // epilogue bias (may be null MODE2)
    const int* __restrict__ isrc, const int* __restrict__ idst,    // MODE 3
    const float* __restrict__ p3,                          // MODE 3
    float* Cout, float* __restrict__ score, int M) {
  __shared__ short lds[2][LDS_SHORTS];

  const int tid = threadIdx.x;
  const int lane = tid & 63;
  const int wid = tid >> 6;
  const int wr = wid >> 2, wc = wid & 3;   // 2 x 4 wave grid; per-wave 64 rows x 128 cols
  const int ln31 = lane & 31, lh2 = lane >> 5;
  const int m0 = blockIdx.x * BM;

  // ---- staging mapping: thread t owns row (t>>2), 8-float chunk (t&3) ----
  const int rowA = tid >> 2;
  const int cA = tid & 3;
  const int kq = cA * 8;
  const int pA = cA ^ ((rowA >> 1) & 3);   // swizzled physical chunk for A writes

  const float* gA;
  const float* gA2 = nullptr;
  if constexpr (MODE == 3) {
    int e = m0 + rowA; if (e > M - 1) e = M - 1;
    gA  = A  + (size_t)isrc[e] * HID + kq;
    gA2 = A2 + (size_t)idst[e] * HID + kq;
  } else {
    int r = m0 + rowA; if (r > M - 1) r = M - 1;
    gA = A + (size_t)r * HID + kq;
  }

  f32x16 acc[2][4];
#pragma unroll
  for (int i = 0; i < 2; ++i)
#pragma unroll
    for (int j = 0; j < 4; ++j)
#pragma unroll
      for (int r = 0; r < 16; ++r) acc[i][j][r] = 0.f;

  f32x4 a0, a1, v0, v1;

  auto stageB = [&](int ks, short* buf) {
#pragma unroll
    for (int it = 0; it < 4; ++it) {
      int rb = it * 128 + rowA;
      int cB = cA ^ ((rb >> 1) & 3);       // pre-swizzled global source (linear LDS dest)
      const short* gh = Bth + (size_t)rb * HID + ks * BK + cB * 8;
      const short* gl = Btl + (size_t)rb * HID + ks * BK + cB * 8;
      gload_lds16(gh, buf + BH_OFF + rb * BK + cA * 8);
      gload_lds16(gl, buf + BL_OFF + rb * BK + cA * 8);
    }
  };
  auto loadA = [&](int ks) {
    const float* p = gA + ks * BK;
    a0 = *reinterpret_cast<const f32x4*>(p);
    a1 = *reinterpret_cast<const f32x4*>(p + 4);
    if constexpr (MODE == 3) {
      const float* q = gA2 + ks * BK;
      v0 = *reinterpret_cast<const f32x4*>(q);
      v1 = *reinterpret_cast<const f32x4*>(q + 4);
    }
  };
  auto writeA = [&](short* buf) {
    float f[8];
#pragma unroll
    for (int q = 0; q < 4; ++q) { f[q] = a0[q]; f[q + 4] = a1[q]; }
    if constexpr (MODE == 3) {
#pragma unroll
      for (int q = 0; q < 4; ++q) {
        f[q]     = fmaxf(f[q]     + v0[q], 0.f);
        f[q + 4] = fmaxf(f[q + 4] + v1[q], 0.f);
      }
    }
    short8v h8, l8;
#pragma unroll
    for (int q = 0; q < 8; ++q) {
      unsigned ua = __float_as_uint(f[q]);
      h8[q] = (short)(ua >> 16);
      float rem = f[q] - __uint_as_float(ua & 0xffff0000u);
      l8[q] = (short)(__float_as_uint(rem) >> 16);
    }
    *reinterpret_cast<short8v*>(buf + AH_OFF + rowA * BK + pA * 8) = h8;
    *reinterpret_cast<short8v*>(buf + AL_OFF + rowA * BK + pA * 8) = l8;
  };
  auto compute = [&](const short* buf) {
#pragma unroll
    for (int kc = 0; kc < 2; ++kc) {
      const int cl = kc * 2 + lh2;         // logical 8-short chunk within BK
      bf16x8 ah[2], al[2], bh[4], bl[4];
#pragma unroll
      for (int i = 0; i < 2; ++i) {
        int ra = wr * 64 + i * 32 + ln31;
        int p = cl ^ ((ra >> 1) & 3);
        ah[i] = *reinterpret_cast<const bf16x8*>(buf + AH_OFF + ra * BK + p * 8);
        al[i] = *reinterpret_cast<const bf16x8*>(buf + AL_OFF + ra * BK + p * 8);
      }
#pragma unroll
      for (int j = 0; j < 4; ++j) {
        int rb = wc * 128 + j * 32 + ln31;
        int p = cl ^ ((rb >> 1) & 3);
        bh[j] = *reinterpret_cast<const bf16x8*>(buf + BH_OFF + rb * BK + p * 8);
        bl[j] = *reinterpret_cast<const bf16x8*>(buf + BL_OFF + rb * BK + p * 8);
      }
#pragma unroll
      for (int i = 0; i < 2; ++i)
#pragma unroll
        for (int j = 0; j < 4; ++j) {
          acc[i][j] = __builtin_amdgcn_mfma_f32_32x32x16_bf16(ah[i], bh[j], acc[i][j], 0, 0, 0);
          acc[i][j] = __builtin_amdgcn_mfma_f32_32x32x16_bf16(ah[i], bl[j], acc[i][j], 0, 0, 0);
          acc[i][j] = __builtin_amdgcn_mfma_f32_32x32x16_bf16(al[i], bh[j], acc[i][j], 0, 0, 0);
        }
    }
  };

  // ---- prologue ----
  stageB(0, lds[0]);
  loadA(0);
  writeA(lds[0]);
  __syncthreads();

  // ---- main loop: single barrier per K-step, prefetch into other buffer ----
#pragma unroll 2
  for (int ks = 0; ks < KSTEPS; ++ks) {
    short* cur = lds[ks & 1];
    short* nxt = lds[(ks & 1) ^ 1];
    if (ks + 1 < KSTEPS) {
      loadA(ks + 1);       // global->reg, latency hidden under compute
      stageB(ks + 1, nxt); // async DMA into other buffer
    }
    compute(cur);
    if (ks + 1 < KSTEPS) {
      writeA(nxt);         // split + ds_write after compute (T14)
      __syncthreads();
    }
  }

  // ---- epilogue ----
  float bj[4], pj[4];
#pragma unroll
  for (int j = 0; j < 4; ++j) {
    int col = wc * 128 + j * 32 + ln31;
    if constexpr (MODE == 3) { bj[j] = bias[col]; pj[j] = p3[col]; }
    else if constexpr (MODE == 2) { bj[j] = bias ? bias[col] : 0.f; }
    else { bj[j] = bias[col]; }
  }

  if constexpr (MODE == 3) {
#pragma unroll
    for (int i = 0; i < 2; ++i)
#pragma unroll
      for (int r = 0; r < 16; ++r) {
        float pS = 0.f;
#pragma unroll
        for (int j = 0; j < 4; ++j)
          pS += fmaxf(acc[i][j][r] + bj[j], 0.f) * pj[j];
        pS += __shfl_xor(pS, 1);
        pS += __shfl_xor(pS, 2);
        pS += __shfl_xor(pS, 4);
        pS += __shfl_xor(pS, 8);
        pS += __shfl_xor(pS, 16);
        int row = m0 + wr * 64 + i * 32 + (r & 3) + 8 * (r >> 2) + 4 * lh2;
        if (ln31 == 0 && row < M) atomicAdd(&score[row], pS);
      }
  } else {
#pragma unroll
    for (int i = 0; i < 2; ++i)
#pragma unroll
      for (int j = 0; j < 4; ++j) {
        int col = wc * 128 + j * 32 + ln31;
#pragma unroll
        for (int r = 0; r < 16; ++r) {
          int row = m0 + wr * 64 + i * 32 + (r & 3) + 8 * (r >> 2) + 4 * lh2;
          if (row < M) {
            float v = acc[i][j][r];
            if constexpr (MODE == 2) {
              v += bj[j];
            } else {
              v = fmaxf(v + bj[j], 0.f);
            }
            if constexpr (MODE == 1) v += A[(size_t)row * HID + col];
            Cout[(size_t)row * HID + col] = v;
          }
        }
      }
  }
}

extern "C" void kernel_launch(void* const* d_in, const int* in_sizes, int n_in,
                              void* d_out, int out_size, void* d_ws, size_t ws_size,
                              hipStream_t stream) {
  (void)n_in; (void)out_size; (void)ws_size;
  const float* x      = (const float*)d_in[0];
  const int* pos_src  = (const int*)d_in[1];
  const int* pos_dst  = (const int*)d_in[2];
  const int* neg_src  = (const int*)d_in[3];
  const int* neg_dst  = (const int*)d_in[4];
  const float* W1 = (const float*)d_in[5];
  const float* b1 = (const float*)d_in[6];
  const float* W2 = (const float*)d_in[7];
  const float* b2 = (const float*)d_in[8];
  const float* Wo = (const float*)d_in[9];
  const float* bo = (const float*)d_in[10];
  const float* P1w = (const float*)d_in[11];
  const float* P1b = (const float*)d_in[12];
  const float* P2w = (const float*)d_in[13];
  const float* P2b = (const float*)d_in[14];
  const float* P3w = (const float*)d_in[15];
  const float* P3b = (const float*)d_in[16];

  const int N_NODES = in_sizes[0] / HID;  // 100000
  const int E = in_sizes[1];              // 100000
  float* out = (float*)d_out;

  char* ws = (char*)d_ws;
  const size_t actBytes = (size_t)N_NODES * HID * sizeof(float);
  float* buf0 = (float*)ws;                 // h1 -> h -> V (in place)
  float* buf1 = (float*)(ws + actBytes);    // h2 -> U
  short* wp = (short*)(ws + 2 * actBytes);
  short* W1th = wp; wp += 512 * 512;
  short* W1tl = wp; wp += 512 * 512;
  short* W2th = wp; wp += 512 * 512;
  short* W2tl = wp; wp += 512 * 512;
  short* Woth = wp; wp += 512 * 512;
  short* Wotl = wp; wp += 512 * 512;
  short* PTth = wp; wp += 512 * 512;   // P1w top half (rows 0..511)
  short* PTtl = wp; wp += 512 * 512;
  short* PBth = wp; wp += 512 * 512;   // P1w bottom half (rows 512..1023)
  short* PBtl = wp; wp += 512 * 512;
  short* P2th = wp; wp += 512 * 512;
  short* P2tl = wp; wp += 512 * 512;

  trans_split_kernel<<<1024, 256, 0, stream>>>(W1, W1th, W1tl);
  trans_split_kernel<<<1024, 256, 0, stream>>>(W2, W2th, W2tl);
  trans_split_kernel<<<1024, 256, 0, stream>>>(Wo, Woth, Wotl);
  trans_split_kernel<<<1024, 256, 0, stream>>>(P1w, PTth, PTtl);
  trans_split_kernel<<<1024, 256, 0, stream>>>(P1w + (size_t)512 * 512, PBth, PBtl);
  trans_split_kernel<<<1024, 256, 0, stream>>>(P2w, P2th, P2tl);
  init_out_kernel<<<(2 * E + 255) / 256, 256, 0, stream>>>(out, P3b, 2 * E);

  dim3 blk(THREADS);
  dim3 grdN((N_NODES + BM - 1) / BM);
  dim3 grdE((E + BM - 1) / BM);

  // encoder
  gemm_kernel<0><<<grdN, blk, 0, stream>>>(x,    nullptr, W1th, W1tl, b1, nullptr, nullptr, nullptr, buf0, nullptr, N_NODES);
  gemm_kernel<1><<<grdN, blk, 0, stream>>>(buf0, nullptr, W2th, W2tl, b2, nullptr, nullptr, nullptr, buf1, nullptr, N_NODES);
  gemm_kernel<1><<<grdN, blk, 0, stream>>>(buf1, nullptr, Woth, Wotl, bo, nullptr, nullptr, nullptr, buf0, nullptr, N_NODES);

  // U = h@P1top^T + P1b (buf1); V = h@P1bot^T (buf0, in place: rows are block-exclusive)
  gemm_kernel<2><<<grdN, blk, 0, stream>>>(buf0, nullptr, PTth, PTtl, P1b, nullptr, nullptr, nullptr, buf1, nullptr, N_NODES);
  gemm_kernel<2><<<grdN, blk, 0, stream>>>(buf0, nullptr, PBth, PBtl, nullptr, nullptr, nullptr, nullptr, buf0, nullptr, N_NODES);

  // fused edge scoring: A-row = relu(U[s]+V[d]); GEMM P2; relu; dot P3 -> scores
  gemm_kernel<3><<<grdE, blk, 0, stream>>>(buf1, buf0, P2th, P2tl, P2b, pos_src, pos_dst, P3w, nullptr, out, E);
  gemm_kernel<3><<<grdE, blk, 0, stream>>>(buf1, buf0, P2th, P2tl, P2b, neg_src, neg_dst, P3w, nullptr, out + E, E);
}

// Round 3
// 1372.212 us; speedup vs baseline: 1.5211x; 1.2479x over previous
//
#include <hip/hip_runtime.h>
#include <stdint.h>

#define HID 512
#define BM 128
#define BK 16
#define KSTEPS 32

typedef __attribute__((ext_vector_type(8))) short bf16x8;
typedef __attribute__((ext_vector_type(4))) short short4v;
typedef __attribute__((ext_vector_type(4))) float f32x4;
typedef __attribute__((ext_vector_type(16))) float f32x16;

__device__ __forceinline__ unsigned short f2bf_rne(float f) {
  unsigned u = __float_as_uint(f);
  unsigned r = u + 0x7fffu + ((u >> 16) & 1u);
  return (unsigned short)(r >> 16);
}

__device__ __forceinline__ void gload_lds16(const void* g, void* l) {
  auto gp = reinterpret_cast<const __attribute__((address_space(1))) unsigned int*>(
      (unsigned long long)(uintptr_t)g);
  auto lp = reinterpret_cast<__attribute__((address_space(3))) unsigned int*>(
      (unsigned int)(uintptr_t)l);
  __builtin_amdgcn_global_load_lds(gp, lp, 16, 0, 0);
}

// W [512 k][512 n] fp32 -> packed hi/lo bf16, tile layout [x][ks][c][256 n][8 k]
// flat id = x*131072 + ks*4096 + c*2048 + nl*8 + e
__global__ void trans_split_kernel(const float* __restrict__ W,
                                   short* __restrict__ Bth, short* __restrict__ Btl) {
  int id = blockIdx.x * 256 + threadIdx.x;
  int e = id & 7, nl = (id >> 3) & 255, c = (id >> 11) & 1, ks = (id >> 12) & 31,
      x = (id >> 17) & 1;
  int n = x * 256 + nl, k = ks * 16 + c * 8 + e;
  float w = W[(size_t)k * 512 + n];
  unsigned short hi = f2bf_rne(w);
  float rem = w - __uint_as_float(((unsigned)hi) << 16);
  unsigned short lo = f2bf_rne(rem);
  Bth[id] = (short)hi;
  Btl[id] = (short)lo;
}

__global__ void init_out_kernel(float* __restrict__ out, const float* __restrict__ p3b, int n) {
  int id = blockIdx.x * 256 + threadIdx.x;
  if (id < n) out[id] = p3b[0];
}

// MODE: 0 = C = relu(A@Bt^T + bias)
//       1 = C = relu(A@Bt^T + bias) + A               (residual)
//       2 = C = A@Bt^T (+ bias if non-null, no relu)  (U/V projections)
//       3 = score[row] += dot(relu(relu(U[s]+V[d])@Bt^T + bias), p3)
// BNT: per-block N extent (256 -> grid.x=2 via swizzle, 512 threads;
//                          512 -> full width, 1024 threads, in-place-safe)
template <int MODE, int BNT>
__global__ __launch_bounds__(BNT * 2, 4) void gemm_kernel(
    const float* A, const float* A2,
    const short* __restrict__ Bth, const short* __restrict__ Btl,
    const float* __restrict__ bias,
    const int* __restrict__ isrc, const int* __restrict__ idst,
    const float* __restrict__ p3,
    float* Cout, float* __restrict__ score, int M) {
  constexpr int WN = BNT / 64;                 // waves along N
  constexpr int AH = 0;                        // [c][128][8]
  constexpr int AL = 2048;
  constexpr int BH = 4096;                     // [x][c][256][8]
  constexpr int BL = 4096 + BNT * 16;
  constexpr int BUFSZ = 4096 + 2 * BNT * 16;   // shorts

  __shared__ __align__(16) short lds[2][BUFSZ];

  const int tid = threadIdx.x;
  const int lane = tid & 63;
  const int wid = tid >> 6;
  const int wr = wid / WN, wc = wid % WN;      // per-wave 64 rows x 64 cols
  const int ln31 = lane & 31, lh2 = lane >> 5;

  // ---- XCD-paired block swizzle ----
  const int yb = (M + BM - 1) >> 7;            // row blocks
  const int px = (yb + 7) >> 3;                // y-blocks per XCD
  int xblk, y;
  {
    int g = blockIdx.x;
    int c8 = g & 7, idx = g >> 3;
    if (BNT == 256) { xblk = idx & 1; y = c8 * px + (idx >> 1); }
    else            { xblk = 0;       y = c8 * px + idx; }
  }
  if (y >= yb) return;
  const int m0 = y * BM;
  const int n0 = xblk * BNT;

  // ---- A staging mapping: thread t<512 owns row t>>2, float-quad t&3 ----
  const int rowA = tid >> 2;
  const int cA = tid & 3;
  const float* gA = nullptr;
  const float* gA2 = nullptr;
  if (tid < 512) {
    if constexpr (MODE == 3) {
      int e = m0 + rowA; if (e > M - 1) e = M - 1;
      gA  = A  + (size_t)isrc[e] * HID + cA * 4;
      gA2 = A2 + (size_t)idst[e] * HID + cA * 4;
    } else {
      int r = m0 + rowA; if (r > M - 1) r = M - 1;
      gA = A + (size_t)r * HID + cA * 4;
    }
  }

  f32x16 acc[2][2];
#pragma unroll
  for (int i = 0; i < 2; ++i)
#pragma unroll
    for (int j = 0; j < 2; ++j)
#pragma unroll
      for (int r = 0; r < 16; ++r) acc[i][j][r] = 0.f;

  f32x4 a0, v0;

  auto stageB = [&](int ks, short* buf) {
    if constexpr (BNT == 256) {
      const size_t toff = (size_t)(xblk * 32 + ks) * 4096;
      gload_lds16(Bth + toff + tid * 8, buf + BH + tid * 8);
      gload_lds16(Btl + toff + tid * 8, buf + BL + tid * 8);
    } else {
      const int xp = tid >> 9, tt = tid & 511;
      const size_t toff = (size_t)(xp * 32 + ks) * 4096 + tt * 8;
      gload_lds16(Bth + toff, buf + BH + tid * 8);
      gload_lds16(Btl + toff, buf + BL + tid * 8);
    }
  };
  auto loadA = [&](int ks) {
    a0 = *reinterpret_cast<const f32x4*>(gA + ks * BK);
    if constexpr (MODE == 3) v0 = *reinterpret_cast<const f32x4*>(gA2 + ks * BK);
  };
  auto writeA = [&](short* buf) {
    float f[4];
#pragma unroll
    for (int q = 0; q < 4; ++q) {
      f[q] = a0[q];
      if constexpr (MODE == 3) f[q] = fmaxf(f[q] + v0[q], 0.f);
    }
    short4v h4, l4;
#pragma unroll
    for (int q = 0; q < 4; ++q) {
      unsigned ua = __float_as_uint(f[q]);
      h4[q] = (short)(ua >> 16);
      float rem = f[q] - __uint_as_float(ua & 0xffff0000u);
      l4[q] = (short)(__float_as_uint(rem) >> 16);
    }
    const int doff = (cA >> 1) * 1024 + rowA * 8 + (cA & 1) * 4;
    *reinterpret_cast<short4v*>(buf + AH + doff) = h4;
    *reinterpret_cast<short4v*>(buf + AL + doff) = l4;
  };
  auto compute = [&](const short* buf) {
    bf16x8 ah[2], al[2], bh[2], bl[2];
#pragma unroll
    for (int i = 0; i < 2; ++i) {
      const int aoff = lh2 * 1024 + (wr * 64 + i * 32 + ln31) * 8;
      ah[i] = *reinterpret_cast<const bf16x8*>(buf + AH + aoff);
      al[i] = *reinterpret_cast<const bf16x8*>(buf + AL + aoff);
    }
#pragma unroll
    for (int j = 0; j < 2; ++j) {
      const int cb = wc * 64 + j * 32 + ln31;     // block-local col
      const int boff = (cb >> 8) * 4096 + lh2 * 2048 + (cb & 255) * 8;
      bh[j] = *reinterpret_cast<const bf16x8*>(buf + BH + boff);
      bl[j] = *reinterpret_cast<const bf16x8*>(buf + BL + boff);
    }
    __builtin_amdgcn_s_setprio(1);
#pragma unroll
    for (int i = 0; i < 2; ++i)
#pragma unroll
      for (int j = 0; j < 2; ++j) {
        acc[i][j] = __builtin_amdgcn_mfma_f32_32x32x16_bf16(ah[i], bh[j], acc[i][j], 0, 0, 0);
        acc[i][j] = __builtin_amdgcn_mfma_f32_32x32x16_bf16(ah[i], bl[j], acc[i][j], 0, 0, 0);
        acc[i][j] = __builtin_amdgcn_mfma_f32_32x32x16_bf16(al[i], bh[j], acc[i][j], 0, 0, 0);
      }
    __builtin_amdgcn_s_setprio(0);
  };

  // ---- prologue ----
  stageB(0, lds[0]);
  if (tid < 512) { loadA(0); writeA(lds[0]); }
  __syncthreads();

  // ---- main loop: single barrier per K-step, depth-1 prefetch ----
#pragma unroll 2
  for (int ks = 0; ks < KSTEPS; ++ks) {
    short* cur = lds[ks & 1];
    short* nxt = lds[(ks & 1) ^ 1];
    if (ks + 1 < KSTEPS) {
      if (tid < 512) loadA(ks + 1);
      stageB(ks + 1, nxt);
    }
    compute(cur);
    if (ks + 1 < KSTEPS) {
      if (tid < 512) writeA(nxt);
      __syncthreads();
    }
  }

  // ---- epilogue ----
  float bj[2], pj[2];
#pragma unroll
  for (int j = 0; j < 2; ++j) {
    const int gcol = n0 + wc * 64 + j * 32 + ln31;
    if constexpr (MODE == 3) { bj[j] = bias[gcol]; pj[j] = p3[gcol]; }
    else if constexpr (MODE == 2) { bj[j] = bias ? bias[gcol] : 0.f; pj[j] = 0.f; }
    else { bj[j] = bias[gcol]; pj[j] = 0.f; }
  }

  if constexpr (MODE == 3) {
#pragma unroll
    for (int i = 0; i < 2; ++i)
#pragma unroll
      for (int r = 0; r < 16; ++r) {
        float pS = 0.f;
#pragma unroll
        for (int j = 0; j < 2; ++j)
          pS += fmaxf(acc[i][j][r] + bj[j], 0.f) * pj[j];
        pS += __shfl_xor(pS, 1);
        pS += __shfl_xor(pS, 2);
        pS += __shfl_xor(pS, 4);
        pS += __shfl_xor(pS, 8);
        pS += __shfl_xor(pS, 16);
        const int row = m0 + wr * 64 + i * 32 + (r & 3) + 8 * (r >> 2) + 4 * lh2;
        if (ln31 == 0 && row < M) atomicAdd(&score[row], pS);
      }
  } else {
#pragma unroll
    for (int i = 0; i < 2; ++i)
#pragma unroll
      for (int j = 0; j < 2; ++j) {
        const int gcol = n0 + wc * 64 + j * 32 + ln31;
#pragma unroll
        for (int r = 0; r < 16; ++r) {
          const int row = m0 + wr * 64 + i * 32 + (r & 3) + 8 * (r >> 2) + 4 * lh2;
          if (row < M) {
            float v = acc[i][j][r];
            if constexpr (MODE == 2) {
              v += bj[j];
            } else {
              v = fmaxf(v + bj[j], 0.f);
            }
            if constexpr (MODE == 1) v += A[(size_t)row * HID + gcol];
            Cout[(size_t)row * HID + gcol] = v;
          }
        }
      }
  }
}

extern "C" void kernel_launch(void* const* d_in, const int* in_sizes, int n_in,
                              void* d_out, int out_size, void* d_ws, size_t ws_size,
                              hipStream_t stream) {
  (void)n_in; (void)out_size; (void)ws_size;
  const float* x      = (const float*)d_in[0];
  const int* pos_src  = (const int*)d_in[1];
  const int* pos_dst  = (const int*)d_in[2];
  const int* neg_src  = (const int*)d_in[3];
  const int* neg_dst  = (const int*)d_in[4];
  const float* W1 = (const float*)d_in[5];
  const float* b1 = (const float*)d_in[6];
  const float* W2 = (const float*)d_in[7];
  const float* b2 = (const float*)d_in[8];
  const float* Wo = (const float*)d_in[9];
  const float* bo = (const float*)d_in[10];
  const float* P1w = (const float*)d_in[11];
  const float* P1b = (const float*)d_in[12];
  const float* P2w = (const float*)d_in[13];
  const float* P2b = (const float*)d_in[14];
  const float* P3w = (const float*)d_in[15];
  const float* P3b = (const float*)d_in[16];

  const int N_NODES = in_sizes[0] / HID;  // 100000
  const int E = in_sizes[1];              // 100000
  float* out = (float*)d_out;

  char* ws = (char*)d_ws;
  const size_t actBytes = (size_t)N_NODES * HID * sizeof(float);
  float* buf0 = (float*)ws;                 // h1 -> h -> V (in place, BN=512 variant)
  float* buf1 = (float*)(ws + actBytes);    // h2 -> U
  short* wp = (short*)(ws + 2 * actBytes);
  short* W1th = wp; wp += 512 * 512;
  short* W1tl = wp; wp += 512 * 512;
  short* W2th = wp; wp += 512 * 512;
  short* W2tl = wp; wp += 512 * 512;
  short* Woth = wp; wp += 512 * 512;
  short* Wotl = wp; wp += 512 * 512;
  short* PTth = wp; wp += 512 * 512;   // P1w rows 0..511 (src half)
  short* PTtl = wp; wp += 512 * 512;
  short* PBth = wp; wp += 512 * 512;   // P1w rows 512..1023 (dst half)
  short* PBtl = wp; wp += 512 * 512;
  short* P2th = wp; wp += 512 * 512;
  short* P2tl = wp; wp += 512 * 512;

  trans_split_kernel<<<1024, 256, 0, stream>>>(W1, W1th, W1tl);
  trans_split_kernel<<<1024, 256, 0, stream>>>(W2, W2th, W2tl);
  trans_split_kernel<<<1024, 256, 0, stream>>>(Wo, Woth, Wotl);
  trans_split_kernel<<<1024, 256, 0, stream>>>(P1w, PTth, PTtl);
  trans_split_kernel<<<1024, 256, 0, stream>>>(P1w + (size_t)512 * 512, PBth, PBtl);
  trans_split_kernel<<<1024, 256, 0, stream>>>(P2w, P2th, P2tl);
  init_out_kernel<<<(2 * E + 255) / 256, 256, 0, stream>>>(out, P3b, 2 * E);

  const int ybN = (N_NODES + BM - 1) / BM;
  const int pxN = (ybN + 7) / 8;
  const int ybE = (E + BM - 1) / BM;
  const int pxE = (ybE + 7) / 8;
  dim3 g256N(8 * pxN * 2), g512N(8 * pxN), g256E(8 * pxE * 2);
  dim3 b512(512), b1024(1024);

  // encoder
  gemm_kernel<0, 256><<<g256N, b512, 0, stream>>>(x,    nullptr, W1th, W1tl, b1, nullptr, nullptr, nullptr, buf0, nullptr, N_NODES);
  gemm_kernel<1, 256><<<g256N, b512, 0, stream>>>(buf0, nullptr, W2th, W2tl, b2, nullptr, nullptr, nullptr, buf1, nullptr, N_NODES);
  gemm_kernel<1, 256><<<g256N, b512, 0, stream>>>(buf1, nullptr, Woth, Wotl, bo, nullptr, nullptr, nullptr, buf0, nullptr, N_NODES);

  // U = h@P1top^T + P1b (buf0 -> buf1)
  gemm_kernel<2, 256><<<g256N, b512, 0, stream>>>(buf0, nullptr, PTth, PTtl, P1b, nullptr, nullptr, nullptr, buf1, nullptr, N_NODES);
  // V = h@P1bot^T (buf0 -> buf0 in place: BN=512 keeps rows block-exclusive)
  gemm_kernel<2, 512><<<g512N, b1024, 0, stream>>>(buf0, nullptr, PBth, PBtl, nullptr, nullptr, nullptr, nullptr, buf0, nullptr, N_NODES);

  // fused edge scoring: A-row = relu(U[s]+V[d]); GEMM P2; relu; dot P3 -> scores
  gemm_kernel<3, 256><<<g256E, b512, 0, stream>>>(buf1, buf0, P2th, P2tl, P2b, pos_src, pos_dst, P3w, nullptr, out, E);
  gemm_kernel<3, 256><<<g256E, b512, 0, stream>>>(buf1, buf0, P2th, P2tl, P2b, neg_src, neg_dst, P3w, nullptr, out + E, E);
}